// Round 1
// baseline (121.566 us; speedup 1.0000x reference)
//
#include <hip/hip_runtime.h>

using bf16x8 = __attribute__((ext_vector_type(8))) short;
using f32x4  = __attribute__((ext_vector_type(4))) float;

#define B_SZ 8192
#define D_SZ 1024
#define H_SZ 128
#define C_SZ 256
#define T_SZ 16

__device__ __forceinline__ unsigned short f2bf(float f) {
  unsigned int u = __float_as_uint(f);
  return (unsigned short)((u + 0x7fffu + ((u >> 16) & 1u)) >> 16);
}

// ---------------- cast x [B][D] f32 -> bf16 (same layout) ----------------
__global__ __launch_bounds__(256) void cast_x_kernel(const float* __restrict__ src,
                                                     unsigned short* __restrict__ dst, int n4) {
  int i = blockIdx.x * 256 + threadIdx.x;
  const int stride = gridDim.x * 256;
  for (; i < n4; i += stride) {
    float4 v = ((const float4*)src)[i];
    ushort4 o;
    o.x = f2bf(v.x); o.y = f2bf(v.y); o.z = f2bf(v.z); o.w = f2bf(v.w);
    ((ushort4*)dst)[i] = o;
  }
}

// ------- transpose+cast: src[t][R][C] f32 -> dst[t][C][R] bf16 (k-major for MFMA) -------
__global__ __launch_bounds__(256) void transpose_cast_kernel(const float* __restrict__ src,
                                                             unsigned short* __restrict__ dst,
                                                             int R, int C, int cshift) {
  __shared__ float tile[32][257];  // +1 pad: conflict-free column reads
  const int t = blockIdx.y;
  const int r0 = blockIdx.x * 32;
  const float* s = src + ((size_t)t * R + r0) * C;
  const int n = 32 * C;
  for (int idx = threadIdx.x; idx < n; idx += 256)
    tile[idx >> cshift][idx & (C - 1)] = s[idx];
  __syncthreads();
  unsigned short* d = dst + (size_t)t * C * R + r0;
  for (int idx = threadIdx.x; idx < n; idx += 256) {
    int cc = idx >> 5, rr = idx & 31;
    d[(size_t)cc * R + rr] = f2bf(tile[rr][cc]);
  }
}

// ---------------- router: probs[b][t] = softmax(x @ Wr + br) ----------------
// one wave handles 4 rows; Wr row loads shared across the 4 rows
__global__ __launch_bounds__(256) void router_kernel(const float* __restrict__ x,
                                                     const float* __restrict__ Wr,
                                                     const float* __restrict__ br,
                                                     float* __restrict__ out0) {
  const int lane = threadIdx.x & 63;
  const int wid  = threadIdx.x >> 6;
  const int brow = blockIdx.x * 16 + wid * 4;
  float acc[4][16];
#pragma unroll
  for (int r = 0; r < 4; ++r)
#pragma unroll
    for (int tt = 0; tt < 16; ++tt) acc[r][tt] = 0.f;

  for (int it = 0; it < 16; ++it) {
    const int d = it * 64 + lane;
    const float4* w4 = (const float4*)(Wr + (size_t)d * 16);
    float4 wa = w4[0], wb = w4[1], wc = w4[2], wd = w4[3];
    const float wv[16] = {wa.x, wa.y, wa.z, wa.w, wb.x, wb.y, wb.z, wb.w,
                          wc.x, wc.y, wc.z, wc.w, wd.x, wd.y, wd.z, wd.w};
#pragma unroll
    for (int r = 0; r < 4; ++r) {
      const float xv = x[(size_t)(brow + r) * 1024 + d];
#pragma unroll
      for (int tt = 0; tt < 16; ++tt) acc[r][tt] += xv * wv[tt];
    }
  }
#pragma unroll
  for (int off = 32; off >= 1; off >>= 1) {
#pragma unroll
    for (int r = 0; r < 4; ++r)
#pragma unroll
      for (int tt = 0; tt < 16; ++tt) acc[r][tt] += __shfl_xor(acc[r][tt], off);
  }
  if (lane == 0) {
#pragma unroll
    for (int r = 0; r < 4; ++r) {
      float v[16]; float m = -1e30f;
#pragma unroll
      for (int tt = 0; tt < 16; ++tt) { v[tt] = acc[r][tt] + br[tt]; m = fmaxf(m, v[tt]); }
      float ssum = 0.f;
#pragma unroll
      for (int tt = 0; tt < 16; ++tt) { v[tt] = __expf(v[tt] - m); ssum += v[tt]; }
      const float inv = 1.0f / ssum;
      float4* o = (float4*)(out0 + (size_t)(brow + r) * 16);
      o[0] = make_float4(v[0] * inv, v[1] * inv, v[2] * inv, v[3] * inv);
      o[1] = make_float4(v[4] * inv, v[5] * inv, v[6] * inv, v[7] * inv);
      o[2] = make_float4(v[8] * inv, v[9] * inv, v[10] * inv, v[11] * inv);
      o[3] = make_float4(v[12] * inv, v[13] * inv, v[14] * inv, v[15] * inv);
    }
  }
}

// ---------------- fused expert: per (t, 128-row tile) ----------------
// fc1: hT[n][m] = relu-pre acc of W1T[n][:] . x[m][:]  (A=W1T, B=xT)  -> sH[m][k=n] bf16
// fc2: preds[m][c] = sH[m][:] . W2T[c][:]  (A=h, B=W2)
// LDS: sX [128m][64k] 16KB | sW [128n][64k] 16KB | sH [128m][128k] 32KB = 64KB
#define SX_OFF 0
#define SW_OFF 16384
#define SH_OFF 32768

__global__ __launch_bounds__(512, 4) void expert_kernel(
    const unsigned short* __restrict__ xb, const unsigned short* __restrict__ w1b,
    const unsigned short* __restrict__ w2b, const float* __restrict__ b1,
    const float* __restrict__ b2, const float* __restrict__ probs,
    float* __restrict__ out1) {
  __shared__ __align__(16) char smem[65536];
  const int tid  = threadIdx.x;
  const int lane = tid & 63;
  const int w    = tid >> 6;   // 0..7
  const int l16  = lane & 15;
  const int l4   = lane >> 4;  // 0..3

  // XCD-chunked bijective swizzle (1024 = 8 XCD * 128), t fastest within chunk
  const int bid = blockIdx.x;
  const int lid = (bid & 7) * 128 + (bid >> 3);
  const int t   = lid & 15;
  const int b0  = (lid >> 4) * 128;

  // fc1 wave grid: n-quadrant (32) x m-half (64)
  const int wn = w >> 1;
  const int wm = w & 1;

  f32x4 acc1[2][4] = {};

  const unsigned int o0 = (unsigned int)w * 4096u + (unsigned int)lane * 16u;

  for (int kt = 0; kt < 16; ++kt) {
    // stage sX (waves 0-3) + sW (waves 4-7), linear LDS dest, inverse-swizzled source
#pragma unroll
    for (int it = 0; it < 4; ++it) {
      const unsigned int o  = o0 + (unsigned int)it * 1024u;
      const unsigned int oo = o & 16383u;
      const unsigned int p  = oo ^ (((oo >> 7) & 7u) << 4);
      const int row = (int)(p >> 7);
      const int kk  = (int)((p & 127u) >> 1);
      const unsigned short* g = (o < 16384u)
          ? (xb  + (((size_t)(b0 + row)) << 10) + (kt * 64 + kk))
          : (w1b + (((size_t)(t * 128 + row)) << 10) + (kt * 64 + kk));
      __builtin_amdgcn_global_load_lds(
          (const __attribute__((address_space(1))) unsigned int*)g,
          (__attribute__((address_space(3))) unsigned int*)(smem + ((size_t)w * 4096 + (size_t)it * 1024)),
          16, 0, 0);
    }
    __syncthreads();
#pragma unroll
    for (int ks = 0; ks < 2; ++ks) {
      const int k0b = (ks * 32 + l4 * 8) * 2;
      bf16x8 aw[2], bx[4];
#pragma unroll
      for (int ni = 0; ni < 2; ++ni) {
        const int row = wn * 32 + ni * 16 + l16;
        const int byte = (row << 7) + k0b;
        aw[ni] = *(const bf16x8*)(smem + SW_OFF + (byte ^ ((row & 7) << 4)));
      }
#pragma unroll
      for (int mi = 0; mi < 4; ++mi) {
        const int row = wm * 64 + mi * 16 + l16;
        const int byte = (row << 7) + k0b;
        bx[mi] = *(const bf16x8*)(smem + SX_OFF + (byte ^ ((row & 7) << 4)));
      }
#pragma unroll
      for (int ni = 0; ni < 2; ++ni)
#pragma unroll
        for (int mi = 0; mi < 4; ++mi)
          acc1[ni][mi] = __builtin_amdgcn_mfma_f32_16x16x32_bf16(aw[ni], bx[mi], acc1[ni][mi], 0, 0, 0);
    }
    __syncthreads();
  }

  // fc1 epilogue: +b1, relu, cvt bf16, write hT -> sH[m][k=n] (swizzled, 8B stores)
#pragma unroll
  for (int ni = 0; ni < 2; ++ni) {
    const int n0 = wn * 32 + ni * 16 + l4 * 4;
    float bb[4];
#pragma unroll
    for (int r = 0; r < 4; ++r) bb[r] = b1[t * 128 + n0 + r];
#pragma unroll
    for (int mi = 0; mi < 4; ++mi) {
      const int m = wm * 64 + mi * 16 + l16;
      unsigned int pk[2];
#pragma unroll
      for (int h = 0; h < 2; ++h) {
        float v0 = fmaxf(acc1[ni][mi][2 * h + 0] + bb[2 * h + 0], 0.f);
        float v1 = fmaxf(acc1[ni][mi][2 * h + 1] + bb[2 * h + 1], 0.f);
        pk[h] = (unsigned int)f2bf(v0) | ((unsigned int)f2bf(v1) << 16);
      }
      int byte = (m << 8) + n0 * 2;
      byte ^= ((m & 7) << 4);
      *(uint2*)(smem + SH_OFF + byte) = make_uint2(pk[0], pk[1]);
    }
  }
  __syncthreads();

  // fc2 wave grid: m-quadrant (32) x c-half (128)
  const int wm2 = w >> 1;
  const int wc2 = w & 1;
  f32x4 acc2[2][8] = {};
  const unsigned short* w2t = w2b + (size_t)t * C_SZ * H_SZ;

#pragma unroll
  for (int ks = 0; ks < 4; ++ks) {
    const int k0 = ks * 32 + l4 * 8;
    bf16x8 ah[2];
#pragma unroll
    for (int mi = 0; mi < 2; ++mi) {
      const int row = wm2 * 32 + mi * 16 + l16;
      const int byte = (row << 8) + k0 * 2;
      ah[mi] = *(const bf16x8*)(smem + SH_OFF + (byte ^ ((row & 7) << 4)));
    }
#pragma unroll
    for (int ci = 0; ci < 8; ++ci) {
      const int c = wc2 * 128 + ci * 16 + l16;
      bf16x8 bw = *(const bf16x8*)(w2t + (size_t)c * 128 + k0);
#pragma unroll
      for (int mi = 0; mi < 2; ++mi)
        acc2[mi][ci] = __builtin_amdgcn_mfma_f32_16x16x32_bf16(ah[mi], bw, acc2[mi][ci], 0, 0, 0);
    }
  }

  // fc2 epilogue: +b2, * probs, store f32
  const size_t outbase = (size_t)t * B_SZ * C_SZ;
#pragma unroll
  for (int mi = 0; mi < 2; ++mi) {
    const int mrow0 = wm2 * 32 + mi * 16 + l4 * 4;
    float pv[4];
#pragma unroll
    for (int r = 0; r < 4; ++r) pv[r] = probs[(size_t)(b0 + mrow0 + r) * 16 + t];
#pragma unroll
    for (int ci = 0; ci < 8; ++ci) {
      const int c = wc2 * 128 + ci * 16 + l16;
      const float bias = b2[t * 256 + c];
#pragma unroll
      for (int r = 0; r < 4; ++r)
        out1[outbase + (size_t)(b0 + mrow0 + r) * 256 + c] = (acc2[mi][ci][r] + bias) * pv[r];
    }
  }
}

extern "C" void kernel_launch(void* const* d_in, const int* in_sizes, int n_in,
                              void* d_out, int out_size, void* d_ws, size_t ws_size,
                              hipStream_t stream) {
  const float* x  = (const float*)d_in[0];
  const float* Wr = (const float*)d_in[1];
  const float* br = (const float*)d_in[2];
  const float* W1 = (const float*)d_in[3];
  const float* b1 = (const float*)d_in[4];
  const float* W2 = (const float*)d_in[5];
  const float* b2 = (const float*)d_in[6];
  float* out0 = (float*)d_out;                       // [B][T] probs
  float* out1 = out0 + (size_t)B_SZ * T_SZ;          // [T][B][C] preds

  char* ws = (char*)d_ws;
  unsigned short* xb  = (unsigned short*)ws;                               // 16 MiB
  unsigned short* w1b = (unsigned short*)(ws + (size_t)16777216);          // 4 MiB  [T][H][D]
  unsigned short* w2b = (unsigned short*)(ws + (size_t)16777216 + 4194304);// 1 MiB  [T][C][H]

  cast_x_kernel<<<2048, 256, 0, stream>>>(x, xb, (B_SZ * D_SZ) / 4);
  transpose_cast_kernel<<<dim3(D_SZ / 32, T_SZ), 256, 0, stream>>>(W1, w1b, D_SZ, H_SZ, 7);
  transpose_cast_kernel<<<dim3(H_SZ / 32, T_SZ), 256, 0, stream>>>(W2, w2b, H_SZ, C_SZ, 8);
  router_kernel<<<B_SZ / 16, 256, 0, stream>>>(x, Wr, br, out0);
  expert_kernel<<<1024, 512, 0, stream>>>(xb, w1b, w2b, b1, b2, out0, out1);
}

// Round 2
// 109.034 us; speedup vs baseline: 1.1149x; 1.1149x over previous
//
#include <hip/hip_runtime.h>

using bf16x8 = __attribute__((ext_vector_type(8))) short;
using f32x4  = __attribute__((ext_vector_type(4))) float;

#define B_SZ 8192
#define D_SZ 1024
#define H_SZ 128
#define C_SZ 256
#define T_SZ 16

__device__ __forceinline__ unsigned short f2bf(float f) {
  unsigned int u = __float_as_uint(f);
  return (unsigned short)((u + 0x7fffu + ((u >> 16) & 1u)) >> 16);
}

// ---------------- cast x [B][D] f32 -> bf16 (same layout) ----------------
__global__ __launch_bounds__(256) void cast_x_kernel(const float* __restrict__ src,
                                                     unsigned short* __restrict__ dst, int n4) {
  int i = blockIdx.x * 256 + threadIdx.x;
  const int stride = gridDim.x * 256;
  for (; i < n4; i += stride) {
    float4 v = ((const float4*)src)[i];
    ushort4 o;
    o.x = f2bf(v.x); o.y = f2bf(v.y); o.z = f2bf(v.z); o.w = f2bf(v.w);
    ((ushort4*)dst)[i] = o;
  }
}

// ------- transpose+cast: src[t][R][C] f32 -> dst[t][C][R] bf16 (k-major for MFMA) -------
__global__ __launch_bounds__(256) void transpose_cast_kernel(const float* __restrict__ src,
                                                             unsigned short* __restrict__ dst,
                                                             int R, int C, int cshift) {
  __shared__ float tile[32][257];  // +1 pad: conflict-free column reads
  const int t = blockIdx.y;
  const int r0 = blockIdx.x * 32;
  const float* s = src + ((size_t)t * R + r0) * C;
  const int n = 32 * C;
  for (int idx = threadIdx.x; idx < n; idx += 256)
    tile[idx >> cshift][idx & (C - 1)] = s[idx];
  __syncthreads();
  unsigned short* d = dst + (size_t)t * C * R + r0;
  for (int idx = threadIdx.x; idx < n; idx += 256) {
    int cc = idx >> 5, rr = idx & 31;
    d[(size_t)cc * R + rr] = f2bf(tile[rr][cc]);
  }
}

// ---------------- router: probs[b][t] = softmax(x @ Wr + br) ----------------
__global__ __launch_bounds__(256) void router_kernel(const float* __restrict__ x,
                                                     const float* __restrict__ Wr,
                                                     const float* __restrict__ br,
                                                     float* __restrict__ out0) {
  const int lane = threadIdx.x & 63;
  const int wid  = threadIdx.x >> 6;
  const int brow = blockIdx.x * 16 + wid * 4;
  float acc[4][16];
#pragma unroll
  for (int r = 0; r < 4; ++r)
#pragma unroll
    for (int tt = 0; tt < 16; ++tt) acc[r][tt] = 0.f;

  for (int it = 0; it < 16; ++it) {
    const int d = it * 64 + lane;
    const float4* w4 = (const float4*)(Wr + (size_t)d * 16);
    float4 wa = w4[0], wb = w4[1], wc = w4[2], wd = w4[3];
    const float wv[16] = {wa.x, wa.y, wa.z, wa.w, wb.x, wb.y, wb.z, wb.w,
                          wc.x, wc.y, wc.z, wc.w, wd.x, wd.y, wd.z, wd.w};
#pragma unroll
    for (int r = 0; r < 4; ++r) {
      const float xv = x[(size_t)(brow + r) * 1024 + d];
#pragma unroll
      for (int tt = 0; tt < 16; ++tt) acc[r][tt] += xv * wv[tt];
    }
  }
#pragma unroll
  for (int off = 32; off >= 1; off >>= 1) {
#pragma unroll
    for (int r = 0; r < 4; ++r)
#pragma unroll
      for (int tt = 0; tt < 16; ++tt) acc[r][tt] += __shfl_xor(acc[r][tt], off);
  }
  if (lane == 0) {
#pragma unroll
    for (int r = 0; r < 4; ++r) {
      float v[16]; float m = -1e30f;
#pragma unroll
      for (int tt = 0; tt < 16; ++tt) { v[tt] = acc[r][tt] + br[tt]; m = fmaxf(m, v[tt]); }
      float ssum = 0.f;
#pragma unroll
      for (int tt = 0; tt < 16; ++tt) { v[tt] = __expf(v[tt] - m); ssum += v[tt]; }
      const float inv = 1.0f / ssum;
      float4* o = (float4*)(out0 + (size_t)(brow + r) * 16);
      o[0] = make_float4(v[0] * inv, v[1] * inv, v[2] * inv, v[3] * inv);
      o[1] = make_float4(v[4] * inv, v[5] * inv, v[6] * inv, v[7] * inv);
      o[2] = make_float4(v[8] * inv, v[9] * inv, v[10] * inv, v[11] * inv);
      o[3] = make_float4(v[12] * inv, v[13] * inv, v[14] * inv, v[15] * inv);
    }
  }
}

// ---------------- fused expert: per (t, 256-row tile) ----------------
// fc1: 256m x 128n x 1024k, 2-phase dbuf pipeline (stage kt+1 || compute kt).
// LDS: sX dbuf 2x32KB [256][64] | sW dbuf 2x16KB [128][64] | sH [256][128] aliases sX region.
// fc2: 256m x 256c x 128k, A from sH, B (W2) streamed from global (L2-hot).
#define SW_REG 65536

__global__ __launch_bounds__(512, 2) void expert_kernel(
    const unsigned short* __restrict__ xb, const unsigned short* __restrict__ w1b,
    const unsigned short* __restrict__ w2b, const float* __restrict__ b1,
    const float* __restrict__ b2, const float* __restrict__ probs,
    float* __restrict__ out1) {
  __shared__ __align__(16) char smem[98304];
  const int tid  = threadIdx.x;
  const int lane = tid & 63;
  const int w    = tid >> 6;   // 0..7
  const int l16  = lane & 15;
  const int l4   = lane >> 4;  // 0..3

  // XCD-chunked bijective swizzle (512 = 8 XCD * 64), t fastest within chunk
  const int bid = blockIdx.x;
  const int lid = (bid & 7) * 64 + (bid >> 3);
  const int t   = lid & 15;
  const int b0  = (lid >> 4) * 256;   // 32 row-tiles of 256

  // ---- staging precompute: 6 x 16B gload_lds per thread per kt ----
  // it 0..3 -> sX (32KB), it 4..5 -> sW (16KB); linear LDS dest, inverse-swizzled source
  const unsigned short* gp[6];
  unsigned int ldo[6];
#pragma unroll
  for (int it = 0; it < 6; ++it) {
    if (it < 4) {
      const unsigned int o = (unsigned int)w * 4096u + (unsigned int)it * 1024u + (unsigned int)lane * 16u;
      const int row = (int)(o >> 7);
      const int cb  = (int)((o & 127u) ^ (((unsigned)row & 7u) << 4));
      gp[it]  = xb + (size_t)(b0 + row) * 1024 + (cb >> 1);
      ldo[it] = o;
    } else {
      const unsigned int o = (unsigned int)w * 2048u + (unsigned int)(it - 4) * 1024u + (unsigned int)lane * 16u;
      const int row = (int)(o >> 7);
      const int cb  = (int)((o & 127u) ^ (((unsigned)row & 7u) << 4));
      gp[it]  = w1b + (size_t)(t * 128 + row) * 1024 + (cb >> 1);
      ldo[it] = o;
    }
  }

#define STAGE(curbuf, kt)                                                              \
  {                                                                                    \
    _Pragma("unroll")                                                                  \
    for (int it = 0; it < 6; ++it) {                                                   \
      const unsigned short* g = gp[it] + (kt) * 64;                                    \
      char* dd = smem + (it < 4 ? (curbuf) * 32768 + (int)ldo[it]                      \
                                : SW_REG + (curbuf) * 16384 + (int)ldo[it]);           \
      __builtin_amdgcn_global_load_lds(                                                \
          (const __attribute__((address_space(1))) unsigned int*)g,                    \
          (__attribute__((address_space(3))) unsigned int*)dd, 16, 0, 0);              \
    }                                                                                  \
  }

  // fc1 wave grid: wn (2 n-halves of 64) x wm (4 m-quads of 64)
  const int wn = w & 1;
  const int wm = w >> 1;
  f32x4 acc1[4][4] = {};

#define FC1_COMPUTE(curbuf)                                                            \
  {                                                                                    \
    const int bx_base = (curbuf) * 32768;                                              \
    const int aw_base = SW_REG + (curbuf) * 16384;                                     \
    _Pragma("unroll")                                                                  \
    for (int ks = 0; ks < 2; ++ks) {                                                   \
      const int cb = ks * 64 + l4 * 16;                                                \
      bf16x8 aw[4], bx[4];                                                             \
      _Pragma("unroll")                                                                \
      for (int ni = 0; ni < 4; ++ni) {                                                 \
        const int row = wn * 64 + ni * 16 + l16;                                       \
        aw[ni] = *(const bf16x8*)(smem + aw_base + (row << 7) + (cb ^ ((row & 7) << 4)));\
      }                                                                                \
      _Pragma("unroll")                                                                \
      for (int mi = 0; mi < 4; ++mi) {                                                 \
        const int row = wm * 64 + mi * 16 + l16;                                       \
        bx[mi] = *(const bf16x8*)(smem + bx_base + (row << 7) + (cb ^ ((row & 7) << 4)));\
      }                                                                                \
      _Pragma("unroll")                                                                \
      for (int ni = 0; ni < 4; ++ni)                                                   \
        _Pragma("unroll")                                                              \
        for (int mi = 0; mi < 4; ++mi)                                                 \
          acc1[ni][mi] = __builtin_amdgcn_mfma_f32_16x16x32_bf16(aw[ni], bx[mi], acc1[ni][mi], 0, 0, 0); \
    }                                                                                  \
  }

  STAGE(0, 0);
  __syncthreads();
  int cur = 0;
  for (int kt = 0; kt < 15; ++kt) {
    STAGE(cur ^ 1, kt + 1);
    FC1_COMPUTE(cur);
    __syncthreads();
    cur ^= 1;
  }
  FC1_COMPUTE(cur);
  __syncthreads();  // all waves done reading sX/sW before sH (aliased) writes

  // fc1 epilogue: +b1, relu, cvt bf16, write hT -> sH[m][k=n] (swizzled, 8B stores)
#pragma unroll
  for (int ni = 0; ni < 4; ++ni) {
    const int n0 = wn * 64 + ni * 16 + l4 * 4;
    float bb[4];
#pragma unroll
    for (int r = 0; r < 4; ++r) bb[r] = b1[t * 128 + n0 + r];
#pragma unroll
    for (int mi = 0; mi < 4; ++mi) {
      const int m = wm * 64 + mi * 16 + l16;
      unsigned int pk[2];
#pragma unroll
      for (int h = 0; h < 2; ++h) {
        float v0 = fmaxf(acc1[ni][mi][2 * h + 0] + bb[2 * h + 0], 0.f);
        float v1 = fmaxf(acc1[ni][mi][2 * h + 1] + bb[2 * h + 1], 0.f);
        pk[h] = (unsigned int)f2bf(v0) | ((unsigned int)f2bf(v1) << 16);
      }
      const int byte = (m << 8) + ((n0 * 2) ^ ((m & 7) << 4));
      *(uint2*)(smem + byte) = make_uint2(pk[0], pk[1]);
    }
  }
  __syncthreads();

  // fc2: wave grid wm2 (4 m-quads of 64) x wc (2 c-halves of 128)
  const int wm2 = w >> 1;
  const int wc  = w & 1;
  f32x4 acc2[4][8] = {};
  const unsigned short* w2t = w2b + (size_t)t * C_SZ * H_SZ;

#pragma unroll
  for (int ks = 0; ks < 4; ++ks) {
    const int cb = ks * 64 + l4 * 16;
    bf16x8 ah[4];
#pragma unroll
    for (int mi = 0; mi < 4; ++mi) {
      const int row = wm2 * 64 + mi * 16 + l16;
      ah[mi] = *(const bf16x8*)(smem + (row << 8) + (cb ^ ((row & 7) << 4)));
    }
#pragma unroll
    for (int ci = 0; ci < 8; ++ci) {
      const int c = wc * 128 + ci * 16 + l16;
      bf16x8 bw = *(const bf16x8*)(w2t + (size_t)c * 128 + ks * 32 + l4 * 8);
#pragma unroll
      for (int mi = 0; mi < 4; ++mi)
        acc2[mi][ci] = __builtin_amdgcn_mfma_f32_16x16x32_bf16(ah[mi], bw, acc2[mi][ci], 0, 0, 0);
    }
  }

  // fc2 epilogue: +b2, * probs, store f32
  const size_t outbase = (size_t)t * (size_t)(B_SZ * C_SZ);
#pragma unroll
  for (int mi = 0; mi < 4; ++mi) {
    const int m0 = wm2 * 64 + mi * 16 + l4 * 4;
    float pv[4];
#pragma unroll
    for (int r = 0; r < 4; ++r) pv[r] = probs[(size_t)(b0 + m0 + r) * 16 + t];
#pragma unroll
    for (int ci = 0; ci < 8; ++ci) {
      const int c = wc * 128 + ci * 16 + l16;
      const float bias = b2[t * 256 + c];
#pragma unroll
      for (int r = 0; r < 4; ++r)
        out1[outbase + (size_t)(b0 + m0 + r) * 256 + c] = (acc2[mi][ci][r] + bias) * pv[r];
    }
  }
}

extern "C" void kernel_launch(void* const* d_in, const int* in_sizes, int n_in,
                              void* d_out, int out_size, void* d_ws, size_t ws_size,
                              hipStream_t stream) {
  const float* x  = (const float*)d_in[0];
  const float* Wr = (const float*)d_in[1];
  const float* br = (const float*)d_in[2];
  const float* W1 = (const float*)d_in[3];
  const float* b1 = (const float*)d_in[4];
  const float* W2 = (const float*)d_in[5];
  const float* b2 = (const float*)d_in[6];
  float* out0 = (float*)d_out;                       // [B][T] probs
  float* out1 = out0 + (size_t)B_SZ * T_SZ;          // [T][B][C] preds

  char* ws = (char*)d_ws;
  unsigned short* xb  = (unsigned short*)ws;                                // 16 MiB [B][D]
  unsigned short* w1b = (unsigned short*)(ws + (size_t)16777216);           // 4 MiB  [T][H][D]
  unsigned short* w2b = (unsigned short*)(ws + (size_t)16777216 + 4194304); // 1 MiB  [T][C][H]

  cast_x_kernel<<<2048, 256, 0, stream>>>(x, xb, (B_SZ * D_SZ) / 4);
  transpose_cast_kernel<<<dim3(D_SZ / 32, T_SZ), 256, 0, stream>>>(W1, w1b, D_SZ, H_SZ, 7);
  transpose_cast_kernel<<<dim3(H_SZ / 32, T_SZ), 256, 0, stream>>>(W2, w2b, H_SZ, C_SZ, 8);
  router_kernel<<<B_SZ / 16, 256, 0, stream>>>(x, Wr, br, out0);
  expert_kernel<<<512, 512, 0, stream>>>(xb, w1b, w2b, b1, b2, out0, out1);
}

// Round 4
// 104.190 us; speedup vs baseline: 1.1668x; 1.0465x over previous
//
#include <hip/hip_runtime.h>

using bf16x8 = __attribute__((ext_vector_type(8))) short;
using f32x4  = __attribute__((ext_vector_type(4))) float;

#define B_SZ 8192
#define D_SZ 1024
#define H_SZ 128
#define C_SZ 256
#define T_SZ 16

#define SB __builtin_amdgcn_sched_barrier(0)

__device__ __forceinline__ unsigned short f2bf(float f) {
  unsigned int u = __float_as_uint(f);
  return (unsigned short)((u + 0x7fffu + ((u >> 16) & 1u)) >> 16);
}

// ------- transpose+cast: src[t][R][C] f32 -> dst[t][C][R] bf16 (k-major for MFMA) -------
__global__ __launch_bounds__(256) void transpose_cast_kernel(const float* __restrict__ src,
                                                             unsigned short* __restrict__ dst,
                                                             int R, int C, int cshift) {
  __shared__ float tile[32][257];
  const int t = blockIdx.y;
  const int r0 = blockIdx.x * 32;
  const float* s = src + ((size_t)t * R + r0) * C;
  const int n = 32 * C;
  for (int idx = threadIdx.x; idx < n; idx += 256)
    tile[idx >> cshift][idx & (C - 1)] = s[idx];
  __syncthreads();
  unsigned short* d = dst + (size_t)t * C * R + r0;
  for (int idx = threadIdx.x; idx < n; idx += 256) {
    int cc = idx >> 5, rr = idx & 31;
    d[(size_t)cc * R + rr] = f2bf(tile[rr][cc]);
  }
}

// ------ router + x-cast fused: probs = softmax(x@Wr+br); xb = bf16(x) ------
__global__ __launch_bounds__(256) void router_cast_kernel(const float* __restrict__ x,
                                                          const float* __restrict__ Wr,
                                                          const float* __restrict__ br,
                                                          float* __restrict__ out0,
                                                          unsigned short* __restrict__ xb) {
  const int lane = threadIdx.x & 63;
  const int wid  = threadIdx.x >> 6;
  const int brow = blockIdx.x * 16 + wid * 4;
  float acc[4][16];
#pragma unroll
  for (int r = 0; r < 4; ++r)
#pragma unroll
    for (int tt = 0; tt < 16; ++tt) acc[r][tt] = 0.f;

  for (int it = 0; it < 16; ++it) {
    const int d = it * 64 + lane;
    const float4* w4 = (const float4*)(Wr + (size_t)d * 16);
    float4 wa = w4[0], wb = w4[1], wc = w4[2], wd = w4[3];
    const float wv[16] = {wa.x, wa.y, wa.z, wa.w, wb.x, wb.y, wb.z, wb.w,
                          wc.x, wc.y, wc.z, wc.w, wd.x, wd.y, wd.z, wd.w};
#pragma unroll
    for (int r = 0; r < 4; ++r) {
      const float xv = x[(size_t)(brow + r) * 1024 + d];
      xb[(size_t)(brow + r) * 1024 + d] = f2bf(xv);
#pragma unroll
      for (int tt = 0; tt < 16; ++tt) acc[r][tt] += xv * wv[tt];
    }
  }
#pragma unroll
  for (int off = 32; off >= 1; off >>= 1) {
#pragma unroll
    for (int r = 0; r < 4; ++r)
#pragma unroll
      for (int tt = 0; tt < 16; ++tt) acc[r][tt] += __shfl_xor(acc[r][tt], off);
  }
  if (lane == 0) {
#pragma unroll
    for (int r = 0; r < 4; ++r) {
      float v[16]; float m = -1e30f;
#pragma unroll
      for (int tt = 0; tt < 16; ++tt) { v[tt] = acc[r][tt] + br[tt]; m = fmaxf(m, v[tt]); }
      float ssum = 0.f;
#pragma unroll
      for (int tt = 0; tt < 16; ++tt) { v[tt] = __expf(v[tt] - m); ssum += v[tt]; }
      const float inv = 1.0f / ssum;
      float4* o = (float4*)(out0 + (size_t)(brow + r) * 16);
      o[0] = make_float4(v[0] * inv, v[1] * inv, v[2] * inv, v[3] * inv);
      o[1] = make_float4(v[4] * inv, v[5] * inv, v[6] * inv, v[7] * inv);
      o[2] = make_float4(v[8] * inv, v[9] * inv, v[10] * inv, v[11] * inv);
      o[3] = make_float4(v[12] * inv, v[13] * inv, v[14] * inv, v[15] * inv);
    }
  }
}

// ---------------- fused expert: per (t, 256-row tile) ----------------
// fc1: 256m x 128n x 1024k. Deep pipeline: 2-kt prefetch, counted vmcnt(6),
// raw barriers (no drain), setprio around MFMA clusters.
// LDS: sX dbuf 2x32KB | sW dbuf 2x16KB | sH [256][128]bf16 aliases sX region.
#define SW_REG 65536

__global__ __launch_bounds__(512, 2) void expert_kernel(
    const unsigned short* __restrict__ xb, const unsigned short* __restrict__ w1b,
    const unsigned short* __restrict__ w2b, const float* __restrict__ b1,
    const float* __restrict__ b2, const float* __restrict__ probs,
    float* __restrict__ out1) {
  __shared__ __align__(16) char smem[98304];
  const int tid  = threadIdx.x;
  const int lane = tid & 63;
  const int w    = tid >> 6;   // 0..7
  const int l16  = lane & 15;
  const int l4   = lane >> 4;  // 0..3

  // XCD-chunked bijective swizzle (512 = 8 XCD * 64), t fastest within chunk
  const int bid = blockIdx.x;
  const int lid = (bid & 7) * 64 + (bid >> 3);
  const int t   = lid & 15;
  const int b0  = (lid >> 4) * 256;

  // ---- staging precompute: 6 x 16B gload_lds per thread per kt ----
  const unsigned short* gp[6];
  unsigned int ldo[6];
#pragma unroll
  for (int it = 0; it < 6; ++it) {
    if (it < 4) {
      const unsigned int o = (unsigned int)w * 4096u + (unsigned int)it * 1024u + (unsigned int)lane * 16u;
      const int row = (int)(o >> 7);
      const int cb  = (int)((o & 127u) ^ (((unsigned)row & 7u) << 4));
      gp[it]  = xb + (size_t)(b0 + row) * 1024 + (cb >> 1);
      ldo[it] = o;
    } else {
      const unsigned int o = (unsigned int)w * 2048u + (unsigned int)(it - 4) * 1024u + (unsigned int)lane * 16u;
      const int row = (int)(o >> 7);
      const int cb  = (int)((o & 127u) ^ (((unsigned)row & 7u) << 4));
      gp[it]  = w1b + (size_t)(t * 128 + row) * 1024 + (cb >> 1);
      ldo[it] = o;
    }
  }

  // kt advance folded into the global pointer (builtin's offset arg must be a literal)
#define STAGE(curbuf, kt)                                                              \
  {                                                                                    \
    _Pragma("unroll")                                                                  \
    for (int it = 0; it < 6; ++it) {                                                   \
      const unsigned short* g = gp[it] + (kt) * 64;                                    \
      char* dd = smem + (it < 4 ? (curbuf) * 32768 + (int)ldo[it]                      \
                                : SW_REG + (curbuf) * 16384 + (int)ldo[it]);           \
      __builtin_amdgcn_global_load_lds(                                                \
          (const __attribute__((address_space(1))) unsigned int*)g,                    \
          (__attribute__((address_space(3))) unsigned int*)dd, 16, 0, 0);              \
    }                                                                                  \
  }

  // fc1 wave grid: wn (2 n-halves of 64) x wm (4 m-quads of 64)
  const int wn = w & 1;
  const int wm = w >> 1;
  f32x4 acc1[4][4] = {};

#define FC1_PHASE(curbuf, ks)                                                          \
  {                                                                                    \
    const int bx_base = (curbuf) * 32768;                                              \
    const int aw_base = SW_REG + (curbuf) * 16384;                                     \
    const int cb = (ks) * 64 + l4 * 16;                                                \
    bf16x8 aw[4], bx[4];                                                               \
    _Pragma("unroll")                                                                  \
    for (int ni = 0; ni < 4; ++ni) {                                                   \
      const int row = wn * 64 + ni * 16 + l16;                                         \
      aw[ni] = *(const bf16x8*)(smem + aw_base + (row << 7) + (cb ^ ((row & 7) << 4)));\
    }                                                                                  \
    _Pragma("unroll")                                                                  \
    for (int mi = 0; mi < 4; ++mi) {                                                   \
      const int row = wm * 64 + mi * 16 + l16;                                         \
      bx[mi] = *(const bf16x8*)(smem + bx_base + (row << 7) + (cb ^ ((row & 7) << 4)));\
    }                                                                                  \
    __builtin_amdgcn_s_setprio(1);                                                     \
    _Pragma("unroll")                                                                  \
    for (int ni = 0; ni < 4; ++ni)                                                     \
      _Pragma("unroll")                                                                \
      for (int mi = 0; mi < 4; ++mi)                                                   \
        acc1[ni][mi] = __builtin_amdgcn_mfma_f32_16x16x32_bf16(aw[ni], bx[mi], acc1[ni][mi], 0, 0, 0); \
    __builtin_amdgcn_s_setprio(0);                                                     \
  }

  // prologue: 2-deep prefetch; wait only buf0 (6 newest stay in flight)
  STAGE(0, 0);
  STAGE(1, 1);
  asm volatile("s_waitcnt vmcnt(6)" ::: "memory");
  SB; __builtin_amdgcn_s_barrier(); SB;

#pragma unroll
  for (int kt = 0; kt < 14; ++kt) {
    const int cur = kt & 1;
    FC1_PHASE(cur, 0);
    FC1_PHASE(cur, 1);
    SB; __builtin_amdgcn_s_barrier(); SB;   // all waves done reading buf[cur]
    STAGE(cur, kt + 2);                     // 12 in flight
    asm volatile("s_waitcnt vmcnt(6)" ::: "memory");  // kt+1's 6 landed
    SB; __builtin_amdgcn_s_barrier(); SB;   // buf[cur^1] ready for all
  }
  // kt = 14 (cur=0): no more staging; drain last buffer
  FC1_PHASE(0, 0);
  FC1_PHASE(0, 1);
  SB; __builtin_amdgcn_s_barrier(); SB;
  asm volatile("s_waitcnt vmcnt(0)" ::: "memory");
  SB; __builtin_amdgcn_s_barrier(); SB;
  // kt = 15 (cur=1)
  FC1_PHASE(1, 0);
  FC1_PHASE(1, 1);
  SB; __builtin_amdgcn_s_barrier(); SB;  // reads of sX done before aliased sH writes

  // fc1 epilogue: +b1, relu, cvt bf16, write hT -> sH[m][k=n] (swizzled, 8B stores)
#pragma unroll
  for (int ni = 0; ni < 4; ++ni) {
    const int n0 = wn * 64 + ni * 16 + l4 * 4;
    float bb[4];
#pragma unroll
    for (int r = 0; r < 4; ++r) bb[r] = b1[t * 128 + n0 + r];
#pragma unroll
    for (int mi = 0; mi < 4; ++mi) {
      const int m = wm * 64 + mi * 16 + l16;
      unsigned int pk[2];
#pragma unroll
      for (int h = 0; h < 2; ++h) {
        float v0 = fmaxf(acc1[ni][mi][2 * h + 0] + bb[2 * h + 0], 0.f);
        float v1 = fmaxf(acc1[ni][mi][2 * h + 1] + bb[2 * h + 1], 0.f);
        pk[h] = (unsigned int)f2bf(v0) | ((unsigned int)f2bf(v1) << 16);
      }
      const int byte = (m << 8) + ((n0 * 2) ^ ((m & 7) << 4));
      *(uint2*)(smem + byte) = make_uint2(pk[0], pk[1]);
    }
  }
  asm volatile("s_waitcnt lgkmcnt(0)" ::: "memory");  // ds_writes visible
  SB; __builtin_amdgcn_s_barrier(); SB;

  // fc2: wave grid wm2 (4 m-quads of 64) x wc (2 c-halves of 128)
  const int wm2 = w >> 1;
  const int wc  = w & 1;
  f32x4 acc2[4][8] = {};
  const unsigned short* w2t = w2b + (size_t)t * C_SZ * H_SZ;

#pragma unroll
  for (int ks = 0; ks < 4; ++ks) {
    const int cb = ks * 64 + l4 * 16;
    bf16x8 ah[4];
#pragma unroll
    for (int mi = 0; mi < 4; ++mi) {
      const int row = wm2 * 64 + mi * 16 + l16;
      ah[mi] = *(const bf16x8*)(smem + (row << 8) + (cb ^ ((row & 7) << 4)));
    }
#pragma unroll
    for (int ci = 0; ci < 8; ++ci) {
      const int c = wc * 128 + ci * 16 + l16;
      bf16x8 bw = *(const bf16x8*)(w2t + (size_t)c * 128 + ks * 32 + l4 * 8);
#pragma unroll
      for (int mi = 0; mi < 4; ++mi)
        acc2[mi][ci] = __builtin_amdgcn_mfma_f32_16x16x32_bf16(ah[mi], bw, acc2[mi][ci], 0, 0, 0);
    }
  }

  // fc2 epilogue: +b2, * probs, store f32
  const size_t outbase = (size_t)t * (size_t)(B_SZ * C_SZ);
#pragma unroll
  for (int mi = 0; mi < 4; ++mi) {
    const int m0 = wm2 * 64 + mi * 16 + l4 * 4;
    float pv[4];
#pragma unroll
    for (int r = 0; r < 4; ++r) pv[r] = probs[(size_t)(b0 + m0 + r) * 16 + t];
#pragma unroll
    for (int ci = 0; ci < 8; ++ci) {
      const int c = wc * 128 + ci * 16 + l16;
      const float bias = b2[t * 256 + c];
#pragma unroll
      for (int r = 0; r < 4; ++r)
        out1[outbase + (size_t)(b0 + m0 + r) * 256 + c] = (acc2[mi][ci][r] + bias) * pv[r];
    }
  }
}

extern "C" void kernel_launch(void* const* d_in, const int* in_sizes, int n_in,
                              void* d_out, int out_size, void* d_ws, size_t ws_size,
                              hipStream_t stream) {
  const float* x  = (const float*)d_in[0];
  const float* Wr = (const float*)d_in[1];
  const float* br = (const float*)d_in[2];
  const float* W1 = (const float*)d_in[3];
  const float* b1 = (const float*)d_in[4];
  const float* W2 = (const float*)d_in[5];
  const float* b2 = (const float*)d_in[6];
  float* out0 = (float*)d_out;                       // [B][T] probs
  float* out1 = out0 + (size_t)B_SZ * T_SZ;          // [T][B][C] preds

  char* ws = (char*)d_ws;
  unsigned short* xb  = (unsigned short*)ws;                                // 16 MiB [B][D]
  unsigned short* w1b = (unsigned short*)(ws + (size_t)16777216);           // 4 MiB  [T][H][D]
  unsigned short* w2b = (unsigned short*)(ws + (size_t)16777216 + 4194304); // 1 MiB  [T][C][H]

  router_cast_kernel<<<B_SZ / 16, 256, 0, stream>>>(x, Wr, br, out0, xb);
  transpose_cast_kernel<<<dim3(D_SZ / 32, T_SZ), 256, 0, stream>>>(W1, w1b, D_SZ, H_SZ, 7);
  transpose_cast_kernel<<<dim3(H_SZ / 32, T_SZ), 256, 0, stream>>>(W2, w2b, H_SZ, C_SZ, 8);
  expert_kernel<<<512, 512, 0, stream>>>(xb, w1b, w2b, b1, b2, out0, out1);
}